// Round 13
// baseline (649.159 us; speedup 1.0000x reference)
//
#include <hip/hip_runtime.h>
#include <stdint.h>

// Geometry fixed by the reference: A bits [4,512,512,32], B bits [512,512,32]
#define BATCH 4
#define MDIM  512
#define KDIM  512
#define NDIM  512
#define ROWS  (BATCH * MDIM)   // 2048 flattened output rows
#define BR    4                // C rows per block
#define TPB   512              // threads per block (8 waves)
#define CH    64               // k-chunk size
#define NCH   (KDIM / CH)      // 8 chunks

// Native vector types accepted by __builtin_nontemporal_load/store.
typedef unsigned int u32x4 __attribute__((ext_vector_type(4)));
typedef float        f32x4 __attribute__((ext_vector_type(4)));

// Spread 8 bits so bit i lands at position 4*i (exact integer op).
__device__ __forceinline__ uint32_t spread4(uint32_t x) {
    x = (x | (x << 12)) & 0x000F000Fu;
    x = (x | (x << 6))  & 0x03030303u;
    x = (x | (x << 3))  & 0x11111111u;
    return x;
}

// ---------------------------------------------------------------------------
// Decode B: pulse bits -> u32 words, fully coalesced, 4 KiB/wave (32 words),
// exactly one iteration per wave (262144 words = 32 * 8192 waves). Bit of v
// is bit29 of its IEEE pattern (1.0f = 0x3F800000). NT loads (stream-once).
// ---------------------------------------------------------------------------
__global__ __launch_bounds__(256) void decode_B(const float* __restrict__ Bbits,
                                                uint32_t* __restrict__ Bu) {
    const int lane = threadIdx.x & 63;
    const int waveId = (blockIdx.x * blockDim.x + threadIdx.x) >> 6;
    const int sh = lane & 56;                 // 8*(lane>>3)

    const int wb = waveId * 32;               // 32 words per wave
    const u32x4* sp = (const u32x4*)(Bbits + (size_t)wb * 32);
    uint32_t* dst = Bu + wb;

    u32x4 v0 = __builtin_nontemporal_load(sp + lane);
    u32x4 v1 = __builtin_nontemporal_load(sp + lane + 64);
    u32x4 v2 = __builtin_nontemporal_load(sp + lane + 128);
    u32x4 v3 = __builtin_nontemporal_load(sp + lane + 192);

    unsigned long long m[16];
    m[0]  = __ballot((v0.x >> 29) & 1u);  m[1]  = __ballot((v0.y >> 29) & 1u);
    m[2]  = __ballot((v0.z >> 29) & 1u);  m[3]  = __ballot((v0.w >> 29) & 1u);
    m[4]  = __ballot((v1.x >> 29) & 1u);  m[5]  = __ballot((v1.y >> 29) & 1u);
    m[6]  = __ballot((v1.z >> 29) & 1u);  m[7]  = __ballot((v1.w >> 29) & 1u);
    m[8]  = __ballot((v2.x >> 29) & 1u);  m[9]  = __ballot((v2.y >> 29) & 1u);
    m[10] = __ballot((v2.z >> 29) & 1u);  m[11] = __ballot((v2.w >> 29) & 1u);
    m[12] = __ballot((v3.x >> 29) & 1u);  m[13] = __ballot((v3.y >> 29) & 1u);
    m[14] = __ballot((v3.z >> 29) & 1u);  m[15] = __ballot((v3.w >> 29) & 1u);

    if ((lane & 7) == 0) {
#pragma unroll
        for (int g = 0; g < 4; ++g) {
            uint32_t w = (spread4((uint32_t)(m[4*g+0] >> sh) & 0xFFu) << 0)
                       | (spread4((uint32_t)(m[4*g+1] >> sh) & 0xFFu) << 1)
                       | (spread4((uint32_t)(m[4*g+2] >> sh) & 0xFFu) << 2)
                       | (spread4((uint32_t)(m[4*g+3] >> sh) & 0xFFu) << 3);
            dst[8 * g + (lane >> 3)] = w;    // cached: consumed by gemm
        }
    }
}

// ---------------------------------------------------------------------------
// Fused A-decode + strict-order GEMM + bit-encode.
// Block: 4 rows x 512 cols, 512 threads (8 waves), 1 col/thread, 4 accs.
// Chunk-pipelined (CH=64 k): per chunk, (1) issue next chunk's A-bit loads
// (wave w owns row w>>1, half w&1 -> disjoint 4 KiB stripes; every A-bit
// byte read exactly once chip-wide, NT), (2) k-loop on current LDS buffer
// (A via wave-uniform ds_read_b128 broadcast; B lane-coalesced from
// L2-resident Bu with 1-group register prefetch), (3) ballot+spread4 decode
// of the arrived bits into the other buffer; ONE barrier per chunk.
// Per output element: single accumulator, k=0..511 ascending, one FMA per
// step -> bit-exact vs np.einsum.
// Epilogue: acc -> LDS transpose -> wave-contiguous NT float4 bit stores.
// ---------------------------------------------------------------------------
__global__ __launch_bounds__(TPB) void gemm_fused(const float* __restrict__ Abits,
                                                  const float* __restrict__ Bu,
                                                  float* __restrict__ outbits) {
    __shared__ __align__(16) uint32_t As[2][BR][CH];   // 2 KiB double buffer
    __shared__ uint32_t Us[BR][NDIM];                  // 8 KiB epilogue

    const int tid  = threadIdx.x;
    const int lane = tid & 63;
    const int wv   = tid >> 6;          // 0..7
    const int r    = wv >> 1;           // decode row owned by this wave
    const int h    = wv & 1;            // which 32-word half of the chunk
    const int rowBase = blockIdx.x * BR;
    const int sh = lane & 56;

    // Bit stream for this wave's decode row.
    const float* rowBits = Abits + (size_t)(rowBase + r) * KDIM * 32;

    // ---- prologue: decode chunk 0 into buffer 0 ----
    {
        const u32x4* sp = (const u32x4*)(rowBits + (size_t)(h * 32) * 32);
        u32x4 v0 = __builtin_nontemporal_load(sp + lane);
        u32x4 v1 = __builtin_nontemporal_load(sp + lane + 64);
        u32x4 v2 = __builtin_nontemporal_load(sp + lane + 128);
        u32x4 v3 = __builtin_nontemporal_load(sp + lane + 192);
        unsigned long long m[16];
        m[0]  = __ballot((v0.x >> 29) & 1u);  m[1]  = __ballot((v0.y >> 29) & 1u);
        m[2]  = __ballot((v0.z >> 29) & 1u);  m[3]  = __ballot((v0.w >> 29) & 1u);
        m[4]  = __ballot((v1.x >> 29) & 1u);  m[5]  = __ballot((v1.y >> 29) & 1u);
        m[6]  = __ballot((v1.z >> 29) & 1u);  m[7]  = __ballot((v1.w >> 29) & 1u);
        m[8]  = __ballot((v2.x >> 29) & 1u);  m[9]  = __ballot((v2.y >> 29) & 1u);
        m[10] = __ballot((v2.z >> 29) & 1u);  m[11] = __ballot((v2.w >> 29) & 1u);
        m[12] = __ballot((v3.x >> 29) & 1u);  m[13] = __ballot((v3.y >> 29) & 1u);
        m[14] = __ballot((v3.z >> 29) & 1u);  m[15] = __ballot((v3.w >> 29) & 1u);
        if ((lane & 7) == 0) {
#pragma unroll
            for (int g = 0; g < 4; ++g) {
                uint32_t w = (spread4((uint32_t)(m[4*g+0] >> sh) & 0xFFu) << 0)
                           | (spread4((uint32_t)(m[4*g+1] >> sh) & 0xFFu) << 1)
                           | (spread4((uint32_t)(m[4*g+2] >> sh) & 0xFFu) << 2)
                           | (spread4((uint32_t)(m[4*g+3] >> sh) & 0xFFu) << 3);
                As[0][r][h * 32 + g * 8 + (lane >> 3)] = w;
            }
        }
    }
    __syncthreads();

    // ---- main chunk pipeline ----
    float acc[BR];
#pragma unroll
    for (int rr = 0; rr < BR; ++rr) acc[rr] = 0.0f;

    const float* Bcol = Bu + tid;       // col n = tid
    float bn[8], bc[8];
#pragma unroll
    for (int i = 0; i < 8; ++i) bn[i] = Bcol[(size_t)i * NDIM];

    for (int c = 0; c < NCH; ++c) {
        const int cn = c + 1;
        // (1) issue next chunk's A-bit loads (stay in flight over the k-loop)
        u32x4 v0, v1, v2, v3;
        if (cn < NCH) {
            const u32x4* sp = (const u32x4*)(rowBits + (size_t)(cn * CH + h * 32) * 32);
            v0 = __builtin_nontemporal_load(sp + lane);
            v1 = __builtin_nontemporal_load(sp + lane + 64);
            v2 = __builtin_nontemporal_load(sp + lane + 128);
            v3 = __builtin_nontemporal_load(sp + lane + 192);
        }

        // (2) k-loop over chunk c (strict ascending k, one FMA/step)
        const float* Asf = (const float*)&As[c & 1][0][0];   // [BR][CH]
#pragma unroll
        for (int g8 = 0; g8 < CH / 8; ++g8) {
            const int k0 = c * CH + g8 * 8;     // global k
            const int kk = g8 * 8;              // chunk-local k
#pragma unroll
            for (int i = 0; i < 8; ++i) bc[i] = bn[i];
            const int kp = (k0 + 8) & (KDIM - 1);   // wraps at end (harmless)
#pragma unroll
            for (int i = 0; i < 8; ++i) bn[i] = Bcol[(size_t)(kp + i) * NDIM];

            float4 a0[BR], a1[BR];
#pragma unroll
            for (int rr = 0; rr < BR; ++rr) {
                a0[rr] = *(const float4*)(Asf + rr * CH + kk);       // uniform
                a1[rr] = *(const float4*)(Asf + rr * CH + kk + 4);   // broadcast
            }
#pragma unroll
            for (int rr = 0; rr < BR; ++rr) {
                acc[rr] = __builtin_fmaf(a0[rr].x, bc[0], acc[rr]);
                acc[rr] = __builtin_fmaf(a0[rr].y, bc[1], acc[rr]);
                acc[rr] = __builtin_fmaf(a0[rr].z, bc[2], acc[rr]);
                acc[rr] = __builtin_fmaf(a0[rr].w, bc[3], acc[rr]);
                acc[rr] = __builtin_fmaf(a1[rr].x, bc[4], acc[rr]);
                acc[rr] = __builtin_fmaf(a1[rr].y, bc[5], acc[rr]);
                acc[rr] = __builtin_fmaf(a1[rr].z, bc[6], acc[rr]);
                acc[rr] = __builtin_fmaf(a1[rr].w, bc[7], acc[rr]);
            }
        }

        // (3) finish next chunk's decode into the other buffer
        if (cn < NCH) {
            unsigned long long m[16];
            m[0]  = __ballot((v0.x >> 29) & 1u);  m[1]  = __ballot((v0.y >> 29) & 1u);
            m[2]  = __ballot((v0.z >> 29) & 1u);  m[3]  = __ballot((v0.w >> 29) & 1u);
            m[4]  = __ballot((v1.x >> 29) & 1u);  m[5]  = __ballot((v1.y >> 29) & 1u);
            m[6]  = __ballot((v1.z >> 29) & 1u);  m[7]  = __ballot((v1.w >> 29) & 1u);
            m[8]  = __ballot((v2.x >> 29) & 1u);  m[9]  = __ballot((v2.y >> 29) & 1u);
            m[10] = __ballot((v2.z >> 29) & 1u);  m[11] = __ballot((v2.w >> 29) & 1u);
            m[12] = __ballot((v3.x >> 29) & 1u);  m[13] = __ballot((v3.y >> 29) & 1u);
            m[14] = __ballot((v3.z >> 29) & 1u);  m[15] = __ballot((v3.w >> 29) & 1u);
            if ((lane & 7) == 0) {
#pragma unroll
                for (int g = 0; g < 4; ++g) {
                    uint32_t w = (spread4((uint32_t)(m[4*g+0] >> sh) & 0xFFu) << 0)
                               | (spread4((uint32_t)(m[4*g+1] >> sh) & 0xFFu) << 1)
                               | (spread4((uint32_t)(m[4*g+2] >> sh) & 0xFFu) << 2)
                               | (spread4((uint32_t)(m[4*g+3] >> sh) & 0xFFu) << 3);
                    As[cn & 1][r][h * 32 + g * 8 + (lane >> 3)] = w;
                }
            }
        }
        __syncthreads();   // next-buffer decoded; current-buffer reads done
    }

    // ---- epilogue: transpose through LDS, then coalesced NT bit stores ----
#pragma unroll
    for (int rr = 0; rr < BR; ++rr) Us[rr][tid] = __float_as_uint(acc[rr]);
    __syncthreads();

    float* oBase = outbits + (size_t)rowBase * NDIM * 32;
    const int b = (tid & 7) * 4;
#pragma unroll
    for (int rr = 0; rr < BR; ++rr) {
        float* o = oBase + (size_t)rr * NDIM * 32;
#pragma unroll
        for (int it = 0; it < 8; ++it) {
            uint32_t u = Us[rr][it * 64 + (tid >> 3)];   // 8-lane broadcast
            f32x4 q;
            q.x = (float)((u >> (b + 0)) & 1u);
            q.y = (float)((u >> (b + 1)) & 1u);
            q.z = (float)((u >> (b + 2)) & 1u);
            q.w = (float)((u >> (b + 3)) & 1u);
            __builtin_nontemporal_store(q, (f32x4*)(o + it * 2048 + tid * 4));
        }
    }
}

extern "C" void kernel_launch(void* const* d_in, const int* in_sizes, int n_in,
                              void* d_out, int out_size, void* d_ws, size_t ws_size,
                              hipStream_t stream) {
    const float* Abits = (const float*)d_in[0];   // [4,512,512,32] floats {0,1}
    const float* Bbits = (const float*)d_in[1];   // [512,512,32]
    float* out = (float*)d_out;                   // [4,512,512,32]

    // Workspace: B_u32 (1 MiB)
    uint32_t* B_u = (uint32_t*)d_ws;

    decode_B<<<2048, 256, 0, stream>>>(Bbits, B_u);
    gemm_fused<<<ROWS / BR, TPB, 0, stream>>>(Abits, (const float*)B_u, out);
}

// Round 14
// 79.368 us; speedup vs baseline: 8.1791x; 8.1791x over previous
//
#include <hip/hip_runtime.h>
#include <stdint.h>

// Geometry fixed by the reference: A bits [4,512,512,32], B bits [512,512,32]
#define BATCH 4
#define MDIM  512
#define KDIM  512
#define NDIM  512
#define ROWS  (BATCH * MDIM)   // 2048 flattened output rows
#define BR    2                // C rows per block (2 accs/thread) -> 8192 waves
#define BCOLS 256              // C cols per block (1 col/thread)

#define WORDS_A (ROWS * KDIM)        // 1,048,576 decoded fp32 words of A
#define WORDS_B (KDIM * NDIM)        //   262,144 decoded fp32 words of B
#define WORDS_T (WORDS_A + WORDS_B)  // 1,310,720
#define DEC_BLOCKS 2048
#define DEC_WAVES  (DEC_BLOCKS * 4)              // 8192 waves
#define DEC_ITERS  (WORDS_T / (32 * DEC_WAVES))  // 5 (exact)

// Native vector types accepted by __builtin_nontemporal_load/store.
typedef unsigned int u32x4 __attribute__((ext_vector_type(4)));
typedef float        f32x4 __attribute__((ext_vector_type(4)));

// Spread 8 bits so bit i lands at position 4*i (exact integer op).
__device__ __forceinline__ uint32_t spread4(uint32_t x) {
    x = (x | (x << 12)) & 0x000F000Fu;
    x = (x | (x << 6))  & 0x03030303u;
    x = (x | (x << 3))  & 0x11111111u;
    return x;
}

// ---------------------------------------------------------------------------
// Decode: pulse bits (float {0,1}, bit0=LSB) -> u32 words, fully coalesced.
// Input is streamed ONCE -> non-temporal loads (don't pollute L2).
// Static trip count (5), 4 KiB/wave/iter via four independent 16B/lane.
// Bit of v is bit29 of its IEEE pattern (1.0f = 0x3F800000). Four __ballot
// per KiB collect the wave's 256 bits; lanes (lane&7)==0 assemble 4 words
// each. Integer-exact.
// ---------------------------------------------------------------------------
__global__ __launch_bounds__(256) void decode_all(const float* __restrict__ Abits,
                                                  const float* __restrict__ Bbits,
                                                  uint32_t* __restrict__ Au,
                                                  uint32_t* __restrict__ Bu) {
    const int lane = threadIdx.x & 63;
    const int waveId = (blockIdx.x * blockDim.x + threadIdx.x) >> 6;
    const int sh = lane & 56;                 // 8*(lane>>3)

#pragma unroll
    for (int i = 0; i < DEC_ITERS; ++i) {
        const int wb = (waveId + i * DEC_WAVES) * 32;   // 32 words per wave-iter
        const float* src;
        uint32_t* dst;
        if (wb < WORDS_A) { src = Abits + (size_t)wb * 32;             dst = Au + wb; }
        else              { src = Bbits + (size_t)(wb - WORDS_A) * 32; dst = Bu + (wb - WORDS_A); }

        const u32x4* sp = (const u32x4*)src;
        u32x4 v0 = __builtin_nontemporal_load(sp + lane);         // KiB 0: words  0..7
        u32x4 v1 = __builtin_nontemporal_load(sp + lane + 64);    // KiB 1: words  8..15
        u32x4 v2 = __builtin_nontemporal_load(sp + lane + 128);   // KiB 2: words 16..23
        u32x4 v3 = __builtin_nontemporal_load(sp + lane + 192);   // KiB 3: words 24..31

        unsigned long long m[16];
        m[0]  = __ballot((v0.x >> 29) & 1u);  m[1]  = __ballot((v0.y >> 29) & 1u);
        m[2]  = __ballot((v0.z >> 29) & 1u);  m[3]  = __ballot((v0.w >> 29) & 1u);
        m[4]  = __ballot((v1.x >> 29) & 1u);  m[5]  = __ballot((v1.y >> 29) & 1u);
        m[6]  = __ballot((v1.z >> 29) & 1u);  m[7]  = __ballot((v1.w >> 29) & 1u);
        m[8]  = __ballot((v2.x >> 29) & 1u);  m[9]  = __ballot((v2.y >> 29) & 1u);
        m[10] = __ballot((v2.z >> 29) & 1u);  m[11] = __ballot((v2.w >> 29) & 1u);
        m[12] = __ballot((v3.x >> 29) & 1u);  m[13] = __ballot((v3.y >> 29) & 1u);
        m[14] = __ballot((v3.z >> 29) & 1u);  m[15] = __ballot((v3.w >> 29) & 1u);

        if ((lane & 7) == 0) {
#pragma unroll
            for (int g = 0; g < 4; ++g) {
                uint32_t w = (spread4((uint32_t)(m[4*g+0] >> sh) & 0xFFu) << 0)
                           | (spread4((uint32_t)(m[4*g+1] >> sh) & 0xFFu) << 1)
                           | (spread4((uint32_t)(m[4*g+2] >> sh) & 0xFFu) << 2)
                           | (spread4((uint32_t)(m[4*g+3] >> sh) & 0xFFu) << 3);
                dst[8 * g + (lane >> 3)] = w;    // cached: consumed by gemm
            }
        }
    }
}

// ---------------------------------------------------------------------------
// LDS-free GEMM k-loop (exact np.einsum semantics: per output element, single
// accumulator, k ascending, one FMA per step) + LDS-transposed coalesced
// bit-encode epilogue with non-temporal stores.
// Block: 2 rows x 256 cols, 256 threads; thread = 1 col, 2 row-accs.
// BR=2 -> 2048 blocks = 8 blocks/CU = up to 32 waves/CU: double the TLP of
// the BR=4 variant to hide L2 latency on the lane-coalesced B stream
// (1-group-ahead register prefetch, R8 pattern). A loads wave-uniform
// (scalar path). Epilogue: accs -> 2 KiB LDS, 1 barrier, 64 KiB/block of
// wave-contiguous float4 NT stores.
// ---------------------------------------------------------------------------
__global__ __launch_bounds__(256) void gemm_encode(const float* __restrict__ A,
                                                   const float* __restrict__ B,
                                                   float* __restrict__ outbits) {
    __shared__ uint32_t Us[BR][BCOLS];   // 2 KiB

    const int tid = threadIdx.x;
    const int rowBase = blockIdx.x * BR;
    const int n0 = blockIdx.y * BCOLS;
    const int n = n0 + tid;

    float acc[BR];
#pragma unroll
    for (int r = 0; r < BR; ++r) acc[r] = 0.0f;

    const float* Bcol = B + n;
    const float* Arow = A + (size_t)rowBase * KDIM;

    float bn[8], bc[8];
#pragma unroll
    for (int i = 0; i < 8; ++i) bn[i] = Bcol[(size_t)i * NDIM];   // prologue

#pragma unroll 2
    for (int k0 = 0; k0 < KDIM; k0 += 8) {
#pragma unroll
        for (int i = 0; i < 8; ++i) bc[i] = bn[i];
        const int kp = (k0 + 8) & (KDIM - 1);    // wraps on last iter (harmless)
#pragma unroll
        for (int i = 0; i < 8; ++i) bn[i] = Bcol[(size_t)(kp + i) * NDIM];

        float4 a0[BR], a1[BR];
#pragma unroll
        for (int r = 0; r < BR; ++r) {
            a0[r] = *(const float4*)(Arow + (size_t)r * KDIM + k0);
            a1[r] = *(const float4*)(Arow + (size_t)r * KDIM + k0 + 4);
        }
        // k ascending per element; one FMA per step.
#pragma unroll
        for (int r = 0; r < BR; ++r) {
            acc[r] = __builtin_fmaf(a0[r].x, bc[0], acc[r]);
            acc[r] = __builtin_fmaf(a0[r].y, bc[1], acc[r]);
            acc[r] = __builtin_fmaf(a0[r].z, bc[2], acc[r]);
            acc[r] = __builtin_fmaf(a0[r].w, bc[3], acc[r]);
            acc[r] = __builtin_fmaf(a1[r].x, bc[4], acc[r]);
            acc[r] = __builtin_fmaf(a1[r].y, bc[5], acc[r]);
            acc[r] = __builtin_fmaf(a1[r].z, bc[6], acc[r]);
            acc[r] = __builtin_fmaf(a1[r].w, bc[7], acc[r]);
        }
    }

    // ---- epilogue: transpose through LDS, then coalesced NT bit stores ----
#pragma unroll
    for (int r = 0; r < BR; ++r) Us[r][tid] = __float_as_uint(acc[r]);
    __syncthreads();

    float* oBase = outbits + ((size_t)rowBase * NDIM + n0) * 32;
    const int b = (tid & 7) * 4;
#pragma unroll
    for (int r = 0; r < BR; ++r) {
        float* o = oBase + (size_t)r * NDIM * 32;
#pragma unroll
        for (int it = 0; it < 8; ++it) {
            uint32_t u = Us[r][it * 32 + (tid >> 3)];   // 8-lane broadcast
            f32x4 q;
            q.x = (float)((u >> (b + 0)) & 1u);
            q.y = (float)((u >> (b + 1)) & 1u);
            q.z = (float)((u >> (b + 2)) & 1u);
            q.w = (float)((u >> (b + 3)) & 1u);
            __builtin_nontemporal_store(q, (f32x4*)(o + it * 1024 + tid * 4));
        }
    }
}

extern "C" void kernel_launch(void* const* d_in, const int* in_sizes, int n_in,
                              void* d_out, int out_size, void* d_ws, size_t ws_size,
                              hipStream_t stream) {
    const float* Abits = (const float*)d_in[0];   // [4,512,512,32] floats {0,1}
    const float* Bbits = (const float*)d_in[1];   // [512,512,32]
    float* out = (float*)d_out;                   // [4,512,512,32]

    // Workspace: A_u32 (4 MiB) | B_u32 (1 MiB)
    uint32_t* A_u = (uint32_t*)d_ws;
    uint32_t* B_u = A_u + WORDS_A;

    decode_all<<<DEC_BLOCKS, 256, 0, stream>>>(Abits, Bbits, A_u, B_u);

    dim3 grid(ROWS / BR, NDIM / BCOLS);           // (1024, 2) = 2048 blocks
    gemm_encode<<<grid, 256, 0, stream>>>((const float*)A_u, (const float*)B_u, out);
}

// Round 15
// 78.754 us; speedup vs baseline: 8.2429x; 1.0078x over previous
//
#include <hip/hip_runtime.h>
#include <stdint.h>

// Geometry fixed by the reference: A bits [4,512,512,32], B bits [512,512,32]
#define BATCH 4
#define MDIM  512
#define KDIM  512
#define NDIM  512
#define ROWS  (BATCH * MDIM)   // 2048 flattened output rows
#define BR    4                // C rows per block (4 accs/thread)
#define BCOLS 256              // C cols per block (1 col/thread)
#define KC    16               // k-chunk staged per barrier round
#define NCH   (KDIM / KC)      // 32 chunks

#define WORDS_A (ROWS * KDIM)        // 1,048,576 decoded fp32 words of A
#define WORDS_B (KDIM * NDIM)        //   262,144 decoded fp32 words of B
#define WORDS_T (WORDS_A + WORDS_B)  // 1,310,720
#define DEC_BLOCKS 2048
#define DEC_WAVES  (DEC_BLOCKS * 4)              // 8192 waves
#define DEC_ITERS  (WORDS_T / (32 * DEC_WAVES))  // 5 (exact)

// Native vector types accepted by __builtin_nontemporal_load/store.
typedef unsigned int u32x4 __attribute__((ext_vector_type(4)));
typedef float        f32x4 __attribute__((ext_vector_type(4)));

// Spread 8 bits so bit i lands at position 4*i (exact integer op).
__device__ __forceinline__ uint32_t spread4(uint32_t x) {
    x = (x | (x << 12)) & 0x000F000Fu;
    x = (x | (x << 6))  & 0x03030303u;
    x = (x | (x << 3))  & 0x11111111u;
    return x;
}

// ---------------------------------------------------------------------------
// Decode: pulse bits (float {0,1}, bit0=LSB) -> u32 words, fully coalesced.
// NT loads (stream-once). Static trip count (5), 4 KiB/wave/iter. Bit of v
// is bit29 of its IEEE pattern (1.0f = 0x3F800000). Integer-exact.
// ---------------------------------------------------------------------------
__global__ __launch_bounds__(256) void decode_all(const float* __restrict__ Abits,
                                                  const float* __restrict__ Bbits,
                                                  uint32_t* __restrict__ Au,
                                                  uint32_t* __restrict__ Bu) {
    const int lane = threadIdx.x & 63;
    const int waveId = (blockIdx.x * blockDim.x + threadIdx.x) >> 6;
    const int sh = lane & 56;                 // 8*(lane>>3)

#pragma unroll
    for (int i = 0; i < DEC_ITERS; ++i) {
        const int wb = (waveId + i * DEC_WAVES) * 32;   // 32 words per wave-iter
        const float* src;
        uint32_t* dst;
        if (wb < WORDS_A) { src = Abits + (size_t)wb * 32;             dst = Au + wb; }
        else              { src = Bbits + (size_t)(wb - WORDS_A) * 32; dst = Bu + (wb - WORDS_A); }

        const u32x4* sp = (const u32x4*)src;
        u32x4 v0 = __builtin_nontemporal_load(sp + lane);
        u32x4 v1 = __builtin_nontemporal_load(sp + lane + 64);
        u32x4 v2 = __builtin_nontemporal_load(sp + lane + 128);
        u32x4 v3 = __builtin_nontemporal_load(sp + lane + 192);

        unsigned long long m[16];
        m[0]  = __ballot((v0.x >> 29) & 1u);  m[1]  = __ballot((v0.y >> 29) & 1u);
        m[2]  = __ballot((v0.z >> 29) & 1u);  m[3]  = __ballot((v0.w >> 29) & 1u);
        m[4]  = __ballot((v1.x >> 29) & 1u);  m[5]  = __ballot((v1.y >> 29) & 1u);
        m[6]  = __ballot((v1.z >> 29) & 1u);  m[7]  = __ballot((v1.w >> 29) & 1u);
        m[8]  = __ballot((v2.x >> 29) & 1u);  m[9]  = __ballot((v2.y >> 29) & 1u);
        m[10] = __ballot((v2.z >> 29) & 1u);  m[11] = __ballot((v2.w >> 29) & 1u);
        m[12] = __ballot((v3.x >> 29) & 1u);  m[13] = __ballot((v3.y >> 29) & 1u);
        m[14] = __ballot((v3.z >> 29) & 1u);  m[15] = __ballot((v3.w >> 29) & 1u);

        if ((lane & 7) == 0) {
#pragma unroll
            for (int g = 0; g < 4; ++g) {
                uint32_t w = (spread4((uint32_t)(m[4*g+0] >> sh) & 0xFFu) << 0)
                           | (spread4((uint32_t)(m[4*g+1] >> sh) & 0xFFu) << 1)
                           | (spread4((uint32_t)(m[4*g+2] >> sh) & 0xFFu) << 2)
                           | (spread4((uint32_t)(m[4*g+3] >> sh) & 0xFFu) << 3);
                dst[8 * g + (lane >> 3)] = w;    // cached: consumed by gemm
            }
        }
    }
}

// ---------------------------------------------------------------------------
// GEMM (exact np.einsum semantics: per output element, single accumulator,
// k ascending, one FMA per step) + LDS-transposed NT bit-encode epilogue.
// Block: 4 rows x 256 cols, 256 threads; thread = 1 col, 4 row-accs.
// B is staged per KC=16 chunk via ASYNC global_load_lds (16 KB, double-
// buffered 32 KB -> 4 blocks/CU, 16 waves/CU), prefetched one chunk ahead;
// per k the thread does ONE conflict-free ds_read_b32 + 4 FMAs. A loads are
// wave-uniform (scalar path). B L2 traffic halves vs BR=2 (512 MB), and the
// async DMA tolerates L2 latency without per-lane load TLP.
// ---------------------------------------------------------------------------
__global__ __launch_bounds__(256) void gemm_encode(const float* __restrict__ A,
                                                   const float* __restrict__ B,
                                                   float* __restrict__ outbits) {
    __shared__ __align__(16) float Bs[2][KC][BCOLS];   // 32 KiB double buffer

    const int tid = threadIdx.x;
    const int rowBase = blockIdx.x * BR;
    const int n0 = blockIdx.y * BCOLS;

    float acc[BR];
#pragma unroll
    for (int r = 0; r < BR; ++r) acc[r] = 0.0f;

    const float* Arow = A + (size_t)rowBase * KDIM;

    // Async stage of k-chunk c into buffer buf: 16 KB, linear lane->LDS.
    auto stage = [&](int buf, int c) {
#pragma unroll
        for (int it = 0; it < (KC * BCOLS) / (256 * 4); ++it) {   // 4 iters
            int ci = it * 1024 + tid * 4;     // float index within chunk
            int kk = ci >> 8;                 // /BCOLS
            int j  = ci & (BCOLS - 1);
            const float* gsrc = B + (size_t)(c * KC + kk) * NDIM + n0 + j;
            __builtin_amdgcn_global_load_lds(
                (const __attribute__((address_space(1))) void*)gsrc,
                (__attribute__((address_space(3))) void*)(&Bs[buf][0][0] + ci),
                16, 0, 0);
        }
    };

    stage(0, 0);
    __syncthreads();                  // buffer 0 landed

    for (int c = 0; c < NCH; ++c) {
        if (c + 1 < NCH) stage((c + 1) & 1, c + 1);   // async prefetch

        const int cur = c & 1;
#pragma unroll
        for (int g8 = 0; g8 < KC / 8; ++g8) {         // two 8-k groups
            const int k0 = c * KC + g8 * 8;
            float bc[8];
#pragma unroll
            for (int i = 0; i < 8; ++i) bc[i] = Bs[cur][g8 * 8 + i][tid];

            float4 a0[BR], a1[BR];
#pragma unroll
            for (int r = 0; r < BR; ++r) {
                a0[r] = *(const float4*)(Arow + (size_t)r * KDIM + k0);
                a1[r] = *(const float4*)(Arow + (size_t)r * KDIM + k0 + 4);
            }
            // k ascending per element; one FMA per step.
#pragma unroll
            for (int r = 0; r < BR; ++r) {
                acc[r] = __builtin_fmaf(a0[r].x, bc[0], acc[r]);
                acc[r] = __builtin_fmaf(a0[r].y, bc[1], acc[r]);
                acc[r] = __builtin_fmaf(a0[r].z, bc[2], acc[r]);
                acc[r] = __builtin_fmaf(a0[r].w, bc[3], acc[r]);
                acc[r] = __builtin_fmaf(a1[r].x, bc[4], acc[r]);
                acc[r] = __builtin_fmaf(a1[r].y, bc[5], acc[r]);
                acc[r] = __builtin_fmaf(a1[r].z, bc[6], acc[r]);
                acc[r] = __builtin_fmaf(a1[r].w, bc[7], acc[r]);
            }
        }
        __syncthreads();   // drains vmcnt (next buffer landed) + read fence
    }

    // ---- epilogue: transpose through LDS (alias Bs[0]), NT bit stores ----
    uint32_t* Us = (uint32_t*)&Bs[0][0][0];   // [BR][BCOLS]
#pragma unroll
    for (int r = 0; r < BR; ++r) Us[r * BCOLS + tid] = __float_as_uint(acc[r]);
    __syncthreads();

    float* oBase = outbits + ((size_t)rowBase * NDIM + n0) * 32;
    const int b = (tid & 7) * 4;
#pragma unroll
    for (int r = 0; r < BR; ++r) {
        float* o = oBase + (size_t)r * NDIM * 32;
#pragma unroll
        for (int it = 0; it < 8; ++it) {
            uint32_t u = Us[r * BCOLS + it * 32 + (tid >> 3)];   // 8-lane broadcast
            f32x4 q;
            q.x = (float)((u >> (b + 0)) & 1u);
            q.y = (float)((u >> (b + 1)) & 1u);
            q.z = (float)((u >> (b + 2)) & 1u);
            q.w = (float)((u >> (b + 3)) & 1u);
            __builtin_nontemporal_store(q, (f32x4*)(o + it * 1024 + tid * 4));
        }
    }
}

extern "C" void kernel_launch(void* const* d_in, const int* in_sizes, int n_in,
                              void* d_out, int out_size, void* d_ws, size_t ws_size,
                              hipStream_t stream) {
    const float* Abits = (const float*)d_in[0];   // [4,512,512,32] floats {0,1}
    const float* Bbits = (const float*)d_in[1];   // [512,512,32]
    float* out = (float*)d_out;                   // [4,512,512,32]

    // Workspace: A_u32 (4 MiB) | B_u32 (1 MiB)
    uint32_t* A_u = (uint32_t*)d_ws;
    uint32_t* B_u = A_u + WORDS_A;

    decode_all<<<DEC_BLOCKS, 256, 0, stream>>>(Abits, Bbits, A_u, B_u);

    dim3 grid(ROWS / BR, NDIM / BCOLS);           // (512, 2) = 1024 blocks
    gemm_encode<<<grid, 256, 0, stream>>>((const float*)A_u, (const float*)B_u, out);
}